// Round 7
// baseline (133.836 us; speedup 1.0000x reference)
//
#include <hip/hip_runtime.h>
#include <math.h>

#define HWSZ 262144          // 512*512
#define NCOPY 16             // partial-G copies to spread atomics
#define LAMBD 0.005f
#define SMOOTH 1e-6f
#define NBLOCKS 1024

typedef __attribute__((ext_vector_type(8))) short bf16x8;
typedef __attribute__((ext_vector_type(4))) float f32x4;
typedef __attribute__((ext_vector_type(4))) int i32x4;

// v_rcp_f32: <=1 ulp approx reciprocal; avoids the ~9-instr IEEE div sequence
static __device__ __forceinline__ float rcp_hw(float x) {
    float r; asm("v_rcp_f32 %0, %1" : "=v"(r) : "v"(x)); return r;
}
// v_cvt_pk_bf16_f32: 2 f32 -> packed 2x bf16 (RTE), 1 instr
static __device__ __forceinline__ unsigned int pk_bf16(float lo, float hi) {
    unsigned int r;
    asm("v_cvt_pk_bf16_f32 %0, %1, %2" : "=v"(r) : "v"(lo), "v"(hi));
    return r;
}

// R4's validated gram structure (1024 blocks x 4 tiles, double-buffered LDS,
// one barrier/tile, register-accumulated G, one atomic flush per block) with
// the loss fused as a last-block tail: the separate <<<1,256>>> loss kernel
// was an unprofiled serial tail (16K dependent cold loads on one CU + full
// launch/drain serialization) -- hypothesis: that tail is the 36-vs-15us gap.
__global__ __launch_bounds__(256) void fused_kernel(
    const float* __restrict__ X,   // input  [16][4][512][512]
    const float* __restrict__ T,   // target [16][4][512][512]
    float* __restrict__ Gpart,     // [NCOPY][32][32] partials + ticket counter
    float* __restrict__ out)
{
    __shared__ unsigned short w[2][32][264];

    const int tid  = threadIdx.x;
    const int b    = tid >> 4;             // batch 0..15 (producer role)
    const int px4  = (tid & 15) << 2;      // pixel offset within tile, x4
    const int lane = tid & 63;
    const int wv   = tid >> 6;
    const int r    = lane & 15;
    const int g    = lane >> 4;
    const int I    = (wv >> 1) << 4;       // G row tile base
    const int J    = (wv & 1) << 4;        // G col tile base

    const int tile0 = blockIdx.x << 2;     // 4 tiles of 64 pixels per block

    float fr[2][16], tr[2][16];            // ping-pong staging (static idx after unroll)

    // prologue: issue tile-0 loads
    #pragma unroll
    for (int c = 0; c < 4; ++c) {
        size_t off = (size_t)(b * 4 + c) * HWSZ + (tile0 << 6) + px4;
        *(float4*)&fr[0][c * 4] = *(const float4*)(X + off);
        *(float4*)&tr[0][c * 4] = *(const float4*)(T + off);
    }

    f32x4 acc = {0.f, 0.f, 0.f, 0.f};

    #pragma unroll 4
    for (int t = 0; t < 4; ++t) {
        const int cur = t & 1, nxt = cur ^ 1;   // static after unroll

        // ---- prefetch next tile (overlaps with this tile's math/MFMA) ----
        if (t < 3) {
            #pragma unroll
            for (int c = 0; c < 4; ++c) {
                size_t off = (size_t)(b * 4 + c) * HWSZ + ((tile0 + t + 1) << 6) + px4;
                *(float4*)&fr[nxt][c * 4] = *(const float4*)(X + off);
                *(float4*)&tr[nxt][c * 4] = *(const float4*)(T + off);
            }
        }

        // ---- per-pixel softplus/confidence/softmax (f32), pack bf16 ----
        unsigned int pu[8], qu[8];
        #pragma unroll
        for (int p = 0; p < 4; ++p) {
            float t0 = tr[cur][p],     t1 = tr[cur][4 + p];
            float t2 = tr[cur][8 + p], t3 = tr[cur][12 + p];

            // S = sum_c softplus(t_c) + 4 = log(prod_c (1+e^{t_c})) + 4
            float prod = (1.f + __expf(t0)) * (1.f + __expf(t1))
                       * (1.f + __expf(t2)) * (1.f + __expf(t3));
            float S    = __logf(prod) + 4.0f;
            float conf = __expf(-4.0f * rcp_hw(S));

            // p = softmax(input) (+1 shift cancels; range needs no max-sub)
            float e0 = __expf(fr[cur][p]),     e1 = __expf(fr[cur][4 + p]);
            float e2 = __expf(fr[cur][8 + p]), e3 = __expf(fr[cur][12 + p]);
            float inv = rcp_hw(e0 + e1 + e2 + e3);
            pu[p * 2]     = pk_bf16(e0 * inv, e1 * inv);
            pu[p * 2 + 1] = pk_bf16(e2 * inv, e3 * inv);

            // q = softmax((t+1)*conf)
            float q0 = __expf(fmaf(t0, conf, conf));
            float q1 = __expf(fmaf(t1, conf, conf));
            float q2 = __expf(fmaf(t2, conf, conf));
            float q3 = __expf(fmaf(t3, conf, conf));
            float qi = rcp_hw(q0 + q1 + q2 + q3);
            qu[p * 2]     = pk_bf16(q0 * qi, q1 * qi);
            qu[p * 2 + 1] = pk_bf16(q2 * qi, q3 * qi);
        }

        // column k = px*4 + c (16 consecutive shorts per thread per row)
        *(i32x4*)&w[cur][b][px4 * 4]          = *(const i32x4*)&pu[0];
        *(i32x4*)&w[cur][b][px4 * 4 + 8]      = *(const i32x4*)&pu[4];
        *(i32x4*)&w[cur][16 + b][px4 * 4]     = *(const i32x4*)&qu[0];
        *(i32x4*)&w[cur][16 + b][px4 * 4 + 8] = *(const i32x4*)&qu[4];
        __syncthreads();
        // (reads of w[cur] from tile t-2 are separated from this write by
        //  two barriers; one barrier per tile is sufficient with 2 buffers)

        // ---- MFMA: this wave's 16x16 tile of G, K=256, accumulate ----
        #pragma unroll
        for (int kc = 0; kc < 8; ++kc) {
            bf16x8 a  = *(const bf16x8*)&w[cur][I + r][kc * 32 + g * 8];
            bf16x8 bb = *(const bf16x8*)&w[cur][J + r][kc * 32 + g * 8];
            acc = __builtin_amdgcn_mfma_f32_16x16x32_bf16(a, bb, acc, 0, 0, 0);
        }
    }

    // ---- flush: C/D layout col = lane&15, row = (lane>>4)*4 + reg ----
    float* dst = Gpart + (size_t)(blockIdx.x & (NCOPY - 1)) * 1024;
    #pragma unroll
    for (int v = 0; v < 4; ++v) {
        int row = I + g * 4 + v;
        int col = J + r;
        atomicAdd(&dst[row * 32 + col], acc[v]);
    }

    // ---- ticket: last block to finish computes the loss inline ----
    __shared__ unsigned int amLast;
    __threadfence();                       // make this block's adds visible
    __syncthreads();                       // all threads' adds + fence done
    if (tid == 0) {
        unsigned int* counter = (unsigned int*)(Gpart + NCOPY * 1024);
        amLast = (atomicAdd(counter, 1u) == NBLOCKS - 1);
    }
    __syncthreads();
    if (!amLast) return;

    // last block: reduce the NCOPY partials (atomic fetch-add 0 -> coherent
    // read across XCDs) into the now-dead LDS tile, then the loss math.
    float* G = (float*)w;                  // 1024 floats, reuse LDS
    __shared__ float red[4];
    for (int e = tid; e < 1024; e += 256) {
        float s = 0.f;
        #pragma unroll
        for (int c = 0; c < NCOPY; ++c)
            s += atomicAdd(&Gpart[c * 1024 + e], 0.0f);
        G[e] = s;
    }
    __syncthreads();

    float local = 0.f;
    for (int e = tid; e < 1024; e += 256) {
        int i = e >> 5, j = e & 31;
        float num = 2.f * G[(i << 5) | (j ^ 16)] + SMOOTH;
        float den = G[i * 33] + G[(j ^ 16) * 33] + SMOOTH;
        float D = num / den;
        if (j == (i ^ 16)) D = 0.f;        // mask (i, i±B)
        local += (i == j) ? (D - 1.f) * (D - 1.f) : LAMBD * D * D;
    }

    #pragma unroll
    for (int off = 32; off; off >>= 1) local += __shfl_down(local, off);
    if ((tid & 63) == 0) red[tid >> 6] = local;
    __syncthreads();
    if (tid == 0) out[0] = red[0] + red[1] + red[2] + red[3];
}

extern "C" void kernel_launch(void* const* d_in, const int* in_sizes, int n_in,
                              void* d_out, int out_size, void* d_ws, size_t ws_size,
                              hipStream_t stream)
{
    const float* X = (const float*)d_in[0];   // input
    const float* T = (const float*)d_in[1];   // target
    float* Gpart = (float*)d_ws;              // NCOPY*1024 floats + 1 counter

    hipMemsetAsync(Gpart, 0, (NCOPY * 1024 + 1) * sizeof(float), stream);
    fused_kernel<<<NBLOCKS, 256, 0, stream>>>(X, T, Gpart, (float*)d_out);
}

// Round 8
// 97.503 us; speedup vs baseline: 1.3726x; 1.3726x over previous
//
#include <hip/hip_runtime.h>
#include <math.h>

#define HWSZ 262144          // 512*512
#define NCOPY 16             // partial-G copies to spread atomics
#define LAMBD 0.005f
#define SMOOTH 1e-6f
#define NBLOCKS 1024

typedef __attribute__((ext_vector_type(8))) short bf16x8;
typedef __attribute__((ext_vector_type(4))) float f32x4;
typedef __attribute__((ext_vector_type(4))) int i32x4;

static __device__ __forceinline__ float rcp_hw(float x) {
    float r; asm("v_rcp_f32 %0, %1" : "=v"(r) : "v"(x)); return r;
}
static __device__ __forceinline__ unsigned int pk_bf16(float lo, float hi) {
    unsigned int r;
    asm("v_cvt_pk_bf16_f32 %0, %1, %2" : "=v"(r) : "v"(lo), "v"(hi));
    return r;
}

// ============================ ABLATION PROBES =============================
// Same grid/indexing as gram_kernel. Results kept live with asm sinks
// (rule #17) so nothing is DCE'd and nothing is stored. Dispatch durations
// in the rocprof table decompose the wall: A=loads, B=+math, C=+LDS/MFMA.

__global__ __launch_bounds__(256) void probeA_loads(
    const float* __restrict__ X, const float* __restrict__ T)
{
    const int tid  = threadIdx.x;
    const int b    = tid >> 4;
    const int px4  = (tid & 15) << 2;
    const int tile0 = blockIdx.x << 2;
    f32x4 s = {0.f, 0.f, 0.f, 0.f};
    #pragma unroll
    for (int t = 0; t < 4; ++t) {
        #pragma unroll
        for (int c = 0; c < 4; ++c) {
            size_t off = (size_t)(b * 4 + c) * HWSZ + ((tile0 + t) << 6) + px4;
            s += *(const f32x4*)(X + off);
            s += *(const f32x4*)(T + off);
        }
    }
    asm volatile("" :: "v"(s[0]), "v"(s[1]), "v"(s[2]), "v"(s[3]));
}

__global__ __launch_bounds__(256) void probeB_math(
    const float* __restrict__ X, const float* __restrict__ T)
{
    const int tid  = threadIdx.x;
    const int b    = tid >> 4;
    const int px4  = (tid & 15) << 2;
    const int tile0 = blockIdx.x << 2;
    unsigned int keep = 0u;
    #pragma unroll
    for (int t = 0; t < 4; ++t) {
        float fr[16], tr[16];
        #pragma unroll
        for (int c = 0; c < 4; ++c) {
            size_t off = (size_t)(b * 4 + c) * HWSZ + ((tile0 + t) << 6) + px4;
            *(float4*)&fr[c * 4] = *(const float4*)(X + off);
            *(float4*)&tr[c * 4] = *(const float4*)(T + off);
        }
        #pragma unroll
        for (int p = 0; p < 4; ++p) {
            float t0 = tr[p], t1 = tr[4 + p], t2 = tr[8 + p], t3 = tr[12 + p];
            float prod = (1.f + __expf(t0)) * (1.f + __expf(t1))
                       * (1.f + __expf(t2)) * (1.f + __expf(t3));
            float S    = __logf(prod) + 4.0f;
            float conf = __expf(-4.0f * rcp_hw(S));
            float e0 = __expf(fr[p]),     e1 = __expf(fr[4 + p]);
            float e2 = __expf(fr[8 + p]), e3 = __expf(fr[12 + p]);
            float inv = rcp_hw(e0 + e1 + e2 + e3);
            keep += pk_bf16(e0 * inv, e1 * inv) + pk_bf16(e2 * inv, e3 * inv);
            float q0 = __expf(fmaf(t0, conf, conf));
            float q1 = __expf(fmaf(t1, conf, conf));
            float q2 = __expf(fmaf(t2, conf, conf));
            float q3 = __expf(fmaf(t3, conf, conf));
            float qi = rcp_hw(q0 + q1 + q2 + q3);
            keep += pk_bf16(q0 * qi, q1 * qi) + pk_bf16(q2 * qi, q3 * qi);
        }
    }
    asm volatile("" :: "v"(keep));
}

// probeC: exact R4 structure (dbuf LDS + barriers + MFMA), atomics replaced
// by an asm sink on the accumulator.
__global__ __launch_bounds__(256) void probeC_nostore(
    const float* __restrict__ X, const float* __restrict__ T)
{
    __shared__ unsigned short w[2][32][264];
    const int tid  = threadIdx.x;
    const int b    = tid >> 4;
    const int px4  = (tid & 15) << 2;
    const int lane = tid & 63;
    const int wv   = tid >> 6;
    const int r    = lane & 15;
    const int g    = lane >> 4;
    const int I    = (wv >> 1) << 4;
    const int J    = (wv & 1) << 4;
    const int tile0 = blockIdx.x << 2;

    float fr[2][16], tr[2][16];
    #pragma unroll
    for (int c = 0; c < 4; ++c) {
        size_t off = (size_t)(b * 4 + c) * HWSZ + (tile0 << 6) + px4;
        *(float4*)&fr[0][c * 4] = *(const float4*)(X + off);
        *(float4*)&tr[0][c * 4] = *(const float4*)(T + off);
    }
    f32x4 acc = {0.f, 0.f, 0.f, 0.f};
    #pragma unroll 4
    for (int t = 0; t < 4; ++t) {
        const int cur = t & 1, nxt = cur ^ 1;
        if (t < 3) {
            #pragma unroll
            for (int c = 0; c < 4; ++c) {
                size_t off = (size_t)(b * 4 + c) * HWSZ + ((tile0 + t + 1) << 6) + px4;
                *(float4*)&fr[nxt][c * 4] = *(const float4*)(X + off);
                *(float4*)&tr[nxt][c * 4] = *(const float4*)(T + off);
            }
        }
        unsigned int pu[8], qu[8];
        #pragma unroll
        for (int p = 0; p < 4; ++p) {
            float t0 = tr[cur][p],     t1 = tr[cur][4 + p];
            float t2 = tr[cur][8 + p], t3 = tr[cur][12 + p];
            float prod = (1.f + __expf(t0)) * (1.f + __expf(t1))
                       * (1.f + __expf(t2)) * (1.f + __expf(t3));
            float S    = __logf(prod) + 4.0f;
            float conf = __expf(-4.0f * rcp_hw(S));
            float e0 = __expf(fr[cur][p]),     e1 = __expf(fr[cur][4 + p]);
            float e2 = __expf(fr[cur][8 + p]), e3 = __expf(fr[cur][12 + p]);
            float inv = rcp_hw(e0 + e1 + e2 + e3);
            pu[p * 2]     = pk_bf16(e0 * inv, e1 * inv);
            pu[p * 2 + 1] = pk_bf16(e2 * inv, e3 * inv);
            float q0 = __expf(fmaf(t0, conf, conf));
            float q1 = __expf(fmaf(t1, conf, conf));
            float q2 = __expf(fmaf(t2, conf, conf));
            float q3 = __expf(fmaf(t3, conf, conf));
            float qi = rcp_hw(q0 + q1 + q2 + q3);
            qu[p * 2]     = pk_bf16(q0 * qi, q1 * qi);
            qu[p * 2 + 1] = pk_bf16(q2 * qi, q3 * qi);
        }
        *(i32x4*)&w[cur][b][px4 * 4]          = *(const i32x4*)&pu[0];
        *(i32x4*)&w[cur][b][px4 * 4 + 8]      = *(const i32x4*)&pu[4];
        *(i32x4*)&w[cur][16 + b][px4 * 4]     = *(const i32x4*)&qu[0];
        *(i32x4*)&w[cur][16 + b][px4 * 4 + 8] = *(const i32x4*)&qu[4];
        __syncthreads();
        #pragma unroll
        for (int kc = 0; kc < 8; ++kc) {
            bf16x8 a  = *(const bf16x8*)&w[cur][I + r][kc * 32 + g * 8];
            bf16x8 bb = *(const bf16x8*)&w[cur][J + r][kc * 32 + g * 8];
            acc = __builtin_amdgcn_mfma_f32_16x16x32_bf16(a, bb, acc, 0, 0, 0);
        }
    }
    asm volatile("" :: "v"(acc[0]), "v"(acc[1]), "v"(acc[2]), "v"(acc[3]));
}

// ====================== R4 VALIDATED PIPELINE (exact) ======================
__global__ __launch_bounds__(256) void gram_kernel(
    const float* __restrict__ X, const float* __restrict__ T,
    float* __restrict__ Gpart)
{
    __shared__ unsigned short w[2][32][264];
    const int tid  = threadIdx.x;
    const int b    = tid >> 4;
    const int px4  = (tid & 15) << 2;
    const int lane = tid & 63;
    const int wv   = tid >> 6;
    const int r    = lane & 15;
    const int g    = lane >> 4;
    const int I    = (wv >> 1) << 4;
    const int J    = (wv & 1) << 4;
    const int tile0 = blockIdx.x << 2;

    float fr[2][16], tr[2][16];
    #pragma unroll
    for (int c = 0; c < 4; ++c) {
        size_t off = (size_t)(b * 4 + c) * HWSZ + (tile0 << 6) + px4;
        *(float4*)&fr[0][c * 4] = *(const float4*)(X + off);
        *(float4*)&tr[0][c * 4] = *(const float4*)(T + off);
    }
    f32x4 acc = {0.f, 0.f, 0.f, 0.f};
    #pragma unroll 4
    for (int t = 0; t < 4; ++t) {
        const int cur = t & 1, nxt = cur ^ 1;
        if (t < 3) {
            #pragma unroll
            for (int c = 0; c < 4; ++c) {
                size_t off = (size_t)(b * 4 + c) * HWSZ + ((tile0 + t + 1) << 6) + px4;
                *(float4*)&fr[nxt][c * 4] = *(const float4*)(X + off);
                *(float4*)&tr[nxt][c * 4] = *(const float4*)(T + off);
            }
        }
        unsigned int pu[8], qu[8];
        #pragma unroll
        for (int p = 0; p < 4; ++p) {
            float t0 = tr[cur][p],     t1 = tr[cur][4 + p];
            float t2 = tr[cur][8 + p], t3 = tr[cur][12 + p];
            float prod = (1.f + __expf(t0)) * (1.f + __expf(t1))
                       * (1.f + __expf(t2)) * (1.f + __expf(t3));
            float S    = __logf(prod) + 4.0f;
            float conf = __expf(-4.0f * rcp_hw(S));
            float e0 = __expf(fr[cur][p]),     e1 = __expf(fr[cur][4 + p]);
            float e2 = __expf(fr[cur][8 + p]), e3 = __expf(fr[cur][12 + p]);
            float inv = rcp_hw(e0 + e1 + e2 + e3);
            pu[p * 2]     = pk_bf16(e0 * inv, e1 * inv);
            pu[p * 2 + 1] = pk_bf16(e2 * inv, e3 * inv);
            float q0 = __expf(fmaf(t0, conf, conf));
            float q1 = __expf(fmaf(t1, conf, conf));
            float q2 = __expf(fmaf(t2, conf, conf));
            float q3 = __expf(fmaf(t3, conf, conf));
            float qi = rcp_hw(q0 + q1 + q2 + q3);
            qu[p * 2]     = pk_bf16(q0 * qi, q1 * qi);
            qu[p * 2 + 1] = pk_bf16(q2 * qi, q3 * qi);
        }
        *(i32x4*)&w[cur][b][px4 * 4]          = *(const i32x4*)&pu[0];
        *(i32x4*)&w[cur][b][px4 * 4 + 8]      = *(const i32x4*)&pu[4];
        *(i32x4*)&w[cur][16 + b][px4 * 4]     = *(const i32x4*)&qu[0];
        *(i32x4*)&w[cur][16 + b][px4 * 4 + 8] = *(const i32x4*)&qu[4];
        __syncthreads();
        #pragma unroll
        for (int kc = 0; kc < 8; ++kc) {
            bf16x8 a  = *(const bf16x8*)&w[cur][I + r][kc * 32 + g * 8];
            bf16x8 bb = *(const bf16x8*)&w[cur][J + r][kc * 32 + g * 8];
            acc = __builtin_amdgcn_mfma_f32_16x16x32_bf16(a, bb, acc, 0, 0, 0);
        }
    }
    float* dst = Gpart + (size_t)(blockIdx.x & (NCOPY - 1)) * 1024;
    #pragma unroll
    for (int v = 0; v < 4; ++v) {
        int row = I + g * 4 + v;
        int col = J + r;
        atomicAdd(&dst[row * 32 + col], acc[v]);
    }
}

__global__ __launch_bounds__(256) void loss_kernel(
    const float* __restrict__ Gpart, float* __restrict__ out)
{
    __shared__ float G[1024];
    __shared__ float red[4];
    const int t = threadIdx.x;
    {
        f32x4 s = {0.f, 0.f, 0.f, 0.f};
        #pragma unroll
        for (int c = 0; c < NCOPY; ++c)
            s += *(const f32x4*)&Gpart[c * 1024 + t * 4];
        *(f32x4*)&G[t * 4] = s;
    }
    __syncthreads();
    float local = 0.f;
    for (int e = t; e < 1024; e += 256) {
        int i = e >> 5, j = e & 31;
        float num = 2.f * G[(i << 5) | (j ^ 16)] + SMOOTH;
        float den = G[i * 33] + G[(j ^ 16) * 33] + SMOOTH;
        float D = num / den;
        if (j == (i ^ 16)) D = 0.f;
        local += (i == j) ? (D - 1.f) * (D - 1.f) : LAMBD * D * D;
    }
    #pragma unroll
    for (int off = 32; off; off >>= 1) local += __shfl_down(local, off);
    if ((t & 63) == 0) red[t >> 6] = local;
    __syncthreads();
    if (t == 0) out[0] = red[0] + red[1] + red[2] + red[3];
}

extern "C" void kernel_launch(void* const* d_in, const int* in_sizes, int n_in,
                              void* d_out, int out_size, void* d_ws, size_t ws_size,
                              hipStream_t stream)
{
    const float* X = (const float*)d_in[0];
    const float* T = (const float*)d_in[1];
    float* Gpart = (float*)d_ws;

    hipMemsetAsync(Gpart, 0, NCOPY * 1024 * sizeof(float), stream);
    probeA_loads  <<<NBLOCKS, 256, 0, stream>>>(X, T);
    probeB_math   <<<NBLOCKS, 256, 0, stream>>>(X, T);
    probeC_nostore<<<NBLOCKS, 256, 0, stream>>>(X, T);
    gram_kernel   <<<NBLOCKS, 256, 0, stream>>>(X, T, Gpart);
    loss_kernel   <<<1, 256, 0, stream>>>(Gpart, (float*)d_out);
}

// Round 9
// 58.866 us; speedup vs baseline: 2.2736x; 1.6564x over previous
//
#include <hip/hip_runtime.h>
#include <math.h>

#define HWSZ 262144          // 512*512
#define NCOPY 16             // partial-G copies to spread atomics
#define LAMBD 0.005f
#define SMOOTH 1e-6f
#define WSTR 520             // W row stride (shorts): 512+8 -> 1040 B, 16B-aligned,
                             // word-stride%32==4 (same proven bank class as R4)

typedef __attribute__((ext_vector_type(8))) short bf16x8;
typedef __attribute__((ext_vector_type(4))) float f32x4;

static __device__ __forceinline__ float rcp_hw(float x) {
    float r; asm("v_rcp_f32 %0, %1" : "=v"(r) : "v"(x)); return r;
}
static __device__ __forceinline__ unsigned int pk_bf16(float lo, float hi) {
    unsigned int r;
    asm("v_cvt_pk_bf16_f32 %0, %1, %2" : "=v"(r) : "v"(lo), "v"(hi));
    return r;
}

// p/q math for 4 pixels (one f32x4 slot per channel), pack bf16 c-major:
// pu[c] = {px0px1, px2px3} of channel c.
static __device__ __forceinline__ void pq_math(
    const f32x4 x[4], const f32x4 t[4],
    unsigned int pu[4][2], unsigned int qu[4][2])
{
    float pv[4][4], qv[4][4];
    #pragma unroll
    for (int u = 0; u < 4; ++u) {
        float t0 = t[0][u], t1 = t[1][u], t2 = t[2][u], t3 = t[3][u];
        // S = sum_c softplus(t_c)+4 = log(prod(1+e^t))+4 (range-safe, R3+)
        float prod = (1.f + __expf(t0)) * (1.f + __expf(t1))
                   * (1.f + __expf(t2)) * (1.f + __expf(t3));
        float S    = __logf(prod) + 4.0f;
        float conf = __expf(-4.0f * rcp_hw(S));
        float e0 = __expf(x[0][u]), e1 = __expf(x[1][u]);
        float e2 = __expf(x[2][u]), e3 = __expf(x[3][u]);
        float inv = rcp_hw(e0 + e1 + e2 + e3);
        pv[0][u] = e0 * inv; pv[1][u] = e1 * inv;
        pv[2][u] = e2 * inv; pv[3][u] = e3 * inv;
        float q0 = __expf(fmaf(t0, conf, conf));
        float q1 = __expf(fmaf(t1, conf, conf));
        float q2 = __expf(fmaf(t2, conf, conf));
        float q3 = __expf(fmaf(t3, conf, conf));
        float qi = rcp_hw(q0 + q1 + q2 + q3);
        qv[0][u] = q0 * qi; qv[1][u] = q1 * qi;
        qv[2][u] = q2 * qi; qv[3][u] = q3 * qi;
    }
    #pragma unroll
    for (int c = 0; c < 4; ++c) {
        pu[c][0] = pk_bf16(pv[c][0], pv[c][1]);
        pu[c][1] = pk_bf16(pv[c][2], pv[c][3]);
        qu[c][0] = pk_bf16(qv[c][0], qv[c][1]);
        qu[c][1] = pk_bf16(qv[c][2], qv[c][3]);
    }
}

// ---- calibration probe: m13-style contiguous grid-stride float4 reader ----
__global__ __launch_bounds__(256) void probe_stream(
    const float* __restrict__ X, const float* __restrict__ T)
{
    const size_t n4 = (size_t)16 * 4 * HWSZ / 4;     // float4 count per tensor
    f32x4 s = {0.f, 0.f, 0.f, 0.f};
    for (size_t k = (size_t)blockIdx.x * 256 + threadIdx.x; k < n4;
         k += (size_t)2048 * 256) {
        s += *(const f32x4*)(X + k * 4);
        s += *(const f32x4*)(T + k * 4);
    }
    asm volatile("" :: "v"(s[0]), "v"(s[1]), "v"(s[2]), "v"(s[3]));
}

// ---- gram with fully-contiguous per-wave-instruction loads ----
// Block = 512 threads (8 waves) x 256 px. Wave w owns batches w and w+8:
// each load instr = one (b,c,tensor) panel x 256 px = 1 KB contiguous
// (lane l -> px 4l..4l+3), so the lane holds all 4 channels of its pixels
// in registers -- no transpose. K is c-major (k = c*256 + px). W-tile
// processed in 2 c-halves in one 33 KB buffer (4 barriers). MFMA: wave w ->
// quadrant w&3, K-chunk w>>2 per half, register-accumulated across halves.
// Flush: Gtmp LDS reduce (waves 0-3), 1024 atomics/block (R4 parity).
__global__ __launch_bounds__(512, 4) void gram_kernel(
    const float* __restrict__ X,   // input  [16][4][512][512]
    const float* __restrict__ T,   // target [16][4][512][512]
    float* __restrict__ Gpart)     // [NCOPY][32][32]
{
    __shared__ unsigned short W[32][WSTR];   // 33,280 B (one K-half: 512 cols)
    __shared__ float Gtmp[8][256];           // 8,192 B

    const int tid  = threadIdx.x;
    const int lane = tid & 63;
    const int w    = tid >> 6;     // wave 0..7
    const int r    = lane & 15;
    const int g    = lane >> 4;
    const int q    = w & 3;        // quadrant
    const int ch   = w >> 2;       // K-chunk within half (0/1)
    const int I    = (q >> 1) << 4;
    const int J    = (q & 1) << 4;

    const size_t PX = (size_t)blockIdx.x << 8;   // 256 px per block

    // ---- contiguous loads: 16 x 1KB wave-spans, all in flight ----
    f32x4 xa[4], ta[4], xb[4], tb[4];
    #pragma unroll
    for (int c = 0; c < 4; ++c) {
        xa[c] = *(const f32x4*)(X + (size_t)(w * 4 + c) * HWSZ + PX + lane * 4);
        ta[c] = *(const f32x4*)(T + (size_t)(w * 4 + c) * HWSZ + PX + lane * 4);
        xb[c] = *(const f32x4*)(X + (size_t)((w + 8) * 4 + c) * HWSZ + PX + lane * 4);
        tb[c] = *(const f32x4*)(T + (size_t)((w + 8) * 4 + c) * HWSZ + PX + lane * 4);
    }

    unsigned int puA[4][2], quA[4][2], puB[4][2], quB[4][2];
    pq_math(xa, ta, puA, quA);
    pq_math(xb, tb, puB, quB);

    f32x4 acc = {0.f, 0.f, 0.f, 0.f};

    #pragma unroll
    for (int h = 0; h < 2; ++h) {
        // write this c-half: rows {w, 16+w, 8+w, 24+w}, cols cc*256 + 4*lane
        #pragma unroll
        for (int cc = 0; cc < 2; ++cc) {
            const int c   = h * 2 + cc;
            const int col = cc * 256 + lane * 4;   // byte 512*cc + 8*lane: 2-way free
            *(uint2*)&W[w     ][col] = make_uint2(puA[c][0], puA[c][1]);
            *(uint2*)&W[16 + w][col] = make_uint2(quA[c][0], quA[c][1]);
            *(uint2*)&W[8 + w ][col] = make_uint2(puB[c][0], puB[c][1]);
            *(uint2*)&W[24 + w][col] = make_uint2(quB[c][0], quB[c][1]);
        }
        __syncthreads();
        // MFMA: this wave's quadrant, K'-range [ch*256, ch*256+256)
        #pragma unroll
        for (int kc = 0; kc < 8; ++kc) {
            bf16x8 af = *(const bf16x8*)&W[I + r][ch * 256 + kc * 32 + g * 8];
            bf16x8 bf = *(const bf16x8*)&W[J + r][ch * 256 + kc * 32 + g * 8];
            acc = __builtin_amdgcn_mfma_f32_16x16x32_bf16(af, bf, acc, 0, 0, 0);
        }
        __syncthreads();   // all MFMA reads done before half-2 overwrites W
    }

    // ---- flush: Gtmp reduce (chunk partials), then R4-level atomics ----
    #pragma unroll
    for (int v = 0; v < 4; ++v) Gtmp[w][lane * 4 + v] = acc[v];
    __syncthreads();
    if (w < 4) {
        // waves {w, w+4} share quadrant w (I,J of this wave are correct)
        float* dst = Gpart + (size_t)(blockIdx.x & (NCOPY - 1)) * 1024;
        #pragma unroll
        for (int v = 0; v < 4; ++v) {
            float s = Gtmp[w][lane * 4 + v] + Gtmp[w + 4][lane * 4 + v];
            // C/D layout (m89): col = lane&15, row = (lane>>4)*4 + reg
            atomicAdd(&dst[(I + g * 4 + v) * 32 + (J + r)], s);
        }
    }
}

__global__ __launch_bounds__(256) void loss_kernel(
    const float* __restrict__ Gpart, float* __restrict__ out)
{
    __shared__ float G[1024];
    __shared__ float red[4];
    const int t = threadIdx.x;
    {
        f32x4 s = {0.f, 0.f, 0.f, 0.f};
        #pragma unroll
        for (int c = 0; c < NCOPY; ++c)
            s += *(const f32x4*)&Gpart[c * 1024 + t * 4];
        *(f32x4*)&G[t * 4] = s;
    }
    __syncthreads();
    float local = 0.f;
    for (int e = t; e < 1024; e += 256) {
        int i = e >> 5, j = e & 31;
        float num = 2.f * G[(i << 5) | (j ^ 16)] + SMOOTH;
        float den = G[i * 33] + G[(j ^ 16) * 33] + SMOOTH;
        float D = num / den;
        if (j == (i ^ 16)) D = 0.f;            // mask (i, i±B)
        local += (i == j) ? (D - 1.f) * (D - 1.f) : LAMBD * D * D;
    }
    #pragma unroll
    for (int off = 32; off; off >>= 1) local += __shfl_down(local, off);
    if ((t & 63) == 0) red[t >> 6] = local;
    __syncthreads();
    if (t == 0) out[0] = red[0] + red[1] + red[2] + red[3];
}

extern "C" void kernel_launch(void* const* d_in, const int* in_sizes, int n_in,
                              void* d_out, int out_size, void* d_ws, size_t ws_size,
                              hipStream_t stream)
{
    const float* X = (const float*)d_in[0];   // input
    const float* T = (const float*)d_in[1];   // target
    float* Gpart = (float*)d_ws;              // NCOPY * 1024 floats

    hipMemsetAsync(Gpart, 0, NCOPY * 1024 * sizeof(float), stream);
    probe_stream<<<2048, 256, 0, stream>>>(X, T);            // calibration
    gram_kernel <<<1024, 512, 0, stream>>>(X, T, Gpart);
    loss_kernel <<<1, 256, 0, stream>>>(Gpart, (float*)d_out);
}

// Round 10
// 38.019 us; speedup vs baseline: 3.5203x; 1.5483x over previous
//
#include <hip/hip_runtime.h>
#include <math.h>

#define HWSZ 262144          // 512*512
#define NCOPY 16             // partial-G copies to spread atomics
#define LAMBD 0.005f
#define SMOOTH 1e-6f
#define WSTR 520             // W row stride (shorts): 1040 B, 16B-aligned,
                             // word-stride%32==4 (same bank class as R4's 264)

typedef __attribute__((ext_vector_type(8))) short bf16x8;
typedef __attribute__((ext_vector_type(4))) float f32x4;

static __device__ __forceinline__ float rcp_hw(float x) {
    float r; asm("v_rcp_f32 %0, %1" : "=v"(r) : "v"(x)); return r;
}
static __device__ __forceinline__ unsigned int pk_bf16(float lo, float hi) {
    unsigned int r;
    asm("v_cvt_pk_bf16_f32 %0, %1, %2" : "=v"(r) : "v"(lo), "v"(hi));
    return r;
}

// p/q math for 4 pixels (one f32x4 slot per channel), pack bf16 c-major.
static __device__ __forceinline__ void pq_math(
    const f32x4 x[4], const f32x4 t[4],
    unsigned int pu[4][2], unsigned int qu[4][2])
{
    float pv[4][4], qv[4][4];
    #pragma unroll
    for (int u = 0; u < 4; ++u) {
        float t0 = t[0][u], t1 = t[1][u], t2 = t[2][u], t3 = t[3][u];
        // S = sum_c softplus(t_c)+4 = log(prod(1+e^t))+4 (range-safe)
        float prod = (1.f + __expf(t0)) * (1.f + __expf(t1))
                   * (1.f + __expf(t2)) * (1.f + __expf(t3));
        float S    = __logf(prod) + 4.0f;
        float conf = __expf(-4.0f * rcp_hw(S));
        float e0 = __expf(x[0][u]), e1 = __expf(x[1][u]);
        float e2 = __expf(x[2][u]), e3 = __expf(x[3][u]);
        float inv = rcp_hw(e0 + e1 + e2 + e3);
        pv[0][u] = e0 * inv; pv[1][u] = e1 * inv;
        pv[2][u] = e2 * inv; pv[3][u] = e3 * inv;
        float q0 = __expf(fmaf(t0, conf, conf));
        float q1 = __expf(fmaf(t1, conf, conf));
        float q2 = __expf(fmaf(t2, conf, conf));
        float q3 = __expf(fmaf(t3, conf, conf));
        float qi = rcp_hw(q0 + q1 + q2 + q3);
        qv[0][u] = q0 * qi; qv[1][u] = q1 * qi;
        qv[2][u] = q2 * qi; qv[3][u] = q3 * qi;
    }
    #pragma unroll
    for (int c = 0; c < 4; ++c) {
        pu[c][0] = pk_bf16(pv[c][0], pv[c][1]);
        pu[c][1] = pk_bf16(pv[c][2], pv[c][3]);
        qu[c][0] = pk_bf16(qv[c][0], qv[c][1]);
        qu[c][1] = pk_bf16(qv[c][2], qv[c][3]);
    }
}

// Contiguous-load gram (R9 structure, validated): block = 512 threads x
// 256 px. Wave w owns batches w and w+8; every load instruction is one
// (b,c,tensor) panel x 256 px = 1 KB fully contiguous (lane l -> px
// 4l..4l+3), all 16 issued up front. Lane then holds all 4 channels of its
// pixels -- no transpose. K c-major (k = c*256+px); W processed in 2
// c-halves (4 barriers). MFMA: wave -> quadrant w&3, K-chunk w>>2;
// register-accumulated across halves. Flush: LDS pair-reduce then
// R4-parity atomics (1024/block). Probes (R8/R9) showed math/LDS/MFMA/
// atomics are all hidden under the platform read cap (~34us timed).
__global__ __launch_bounds__(512, 4) void gram_kernel(
    const float* __restrict__ X,   // input  [16][4][512][512]
    const float* __restrict__ T,   // target [16][4][512][512]
    float* __restrict__ Gpart)     // [NCOPY][32][32]
{
    __shared__ unsigned short W[32][WSTR];   // 33,280 B (one K-half: 512 cols)
    __shared__ float Gtmp[8][256];           // 8,192 B

    const int tid  = threadIdx.x;
    const int lane = tid & 63;
    const int w    = tid >> 6;     // wave 0..7
    const int r    = lane & 15;
    const int g    = lane >> 4;
    const int q    = w & 3;        // quadrant
    const int ch   = w >> 2;       // K-chunk within half (0/1)
    const int I    = (q >> 1) << 4;
    const int J    = (q & 1) << 4;

    const size_t PX = (size_t)blockIdx.x << 8;   // 256 px per block

    // ---- contiguous loads: 16 x 1KB wave-spans, all in flight ----
    f32x4 xa[4], ta[4], xb[4], tb[4];
    #pragma unroll
    for (int c = 0; c < 4; ++c) {
        xa[c] = *(const f32x4*)(X + (size_t)(w * 4 + c) * HWSZ + PX + lane * 4);
        ta[c] = *(const f32x4*)(T + (size_t)(w * 4 + c) * HWSZ + PX + lane * 4);
        xb[c] = *(const f32x4*)(X + (size_t)((w + 8) * 4 + c) * HWSZ + PX + lane * 4);
        tb[c] = *(const f32x4*)(T + (size_t)((w + 8) * 4 + c) * HWSZ + PX + lane * 4);
    }

    unsigned int puA[4][2], quA[4][2], puB[4][2], quB[4][2];
    pq_math(xa, ta, puA, quA);
    pq_math(xb, tb, puB, quB);

    f32x4 acc = {0.f, 0.f, 0.f, 0.f};

    #pragma unroll
    for (int h = 0; h < 2; ++h) {
        // write this c-half: rows {w, 16+w, 8+w, 24+w}, cols cc*256 + 4*lane
        #pragma unroll
        for (int cc = 0; cc < 2; ++cc) {
            const int c   = h * 2 + cc;
            const int col = cc * 256 + lane * 4;
            *(uint2*)&W[w     ][col] = make_uint2(puA[c][0], puA[c][1]);
            *(uint2*)&W[16 + w][col] = make_uint2(quA[c][0], quA[c][1]);
            *(uint2*)&W[8 + w ][col] = make_uint2(puB[c][0], puB[c][1]);
            *(uint2*)&W[24 + w][col] = make_uint2(quB[c][0], quB[c][1]);
        }
        __syncthreads();
        // MFMA: this wave's quadrant, K'-range [ch*256, ch*256+256)
        #pragma unroll
        for (int kc = 0; kc < 8; ++kc) {
            bf16x8 af = *(const bf16x8*)&W[I + r][ch * 256 + kc * 32 + g * 8];
            bf16x8 bf = *(const bf16x8*)&W[J + r][ch * 256 + kc * 32 + g * 8];
            acc = __builtin_amdgcn_mfma_f32_16x16x32_bf16(af, bf, acc, 0, 0, 0);
        }
        __syncthreads();   // all MFMA reads done before half-2 overwrites W
    }

    // ---- flush: LDS pair-reduce (waves w / w+4), then atomics ----
    #pragma unroll
    for (int v = 0; v < 4; ++v) Gtmp[w][lane * 4 + v] = acc[v];
    __syncthreads();
    if (w < 4) {
        float* dst = Gpart + (size_t)(blockIdx.x & (NCOPY - 1)) * 1024;
        #pragma unroll
        for (int v = 0; v < 4; ++v) {
            float s = Gtmp[w][lane * 4 + v] + Gtmp[w + 4][lane * 4 + v];
            // C/D layout (m89): col = lane&15, row = (lane>>4)*4 + reg
            atomicAdd(&dst[(I + g * 4 + v) * 32 + (J + r)], s);
        }
    }
}

__global__ __launch_bounds__(256) void loss_kernel(
    const float* __restrict__ Gpart, float* __restrict__ out)
{
    __shared__ float G[1024];
    __shared__ float red[4];
    const int t = threadIdx.x;
    {
        f32x4 s = {0.f, 0.f, 0.f, 0.f};
        #pragma unroll
        for (int c = 0; c < NCOPY; ++c)
            s += *(const f32x4*)&Gpart[c * 1024 + t * 4];
        *(f32x4*)&G[t * 4] = s;
    }
    __syncthreads();
    float local = 0.f;
    for (int e = t; e < 1024; e += 256) {
        int i = e >> 5, j = e & 31;
        float num = 2.f * G[(i << 5) | (j ^ 16)] + SMOOTH;
        float den = G[i * 33] + G[(j ^ 16) * 33] + SMOOTH;
        float D = num / den;
        if (j == (i ^ 16)) D = 0.f;            // mask (i, i±B)
        local += (i == j) ? (D - 1.f) * (D - 1.f) : LAMBD * D * D;
    }
    #pragma unroll
    for (int off = 32; off; off >>= 1) local += __shfl_down(local, off);
    if ((t & 63) == 0) red[t >> 6] = local;
    __syncthreads();
    if (t == 0) out[0] = red[0] + red[1] + red[2] + red[3];
}

extern "C" void kernel_launch(void* const* d_in, const int* in_sizes, int n_in,
                              void* d_out, int out_size, void* d_ws, size_t ws_size,
                              hipStream_t stream)
{
    const float* X = (const float*)d_in[0];   // input
    const float* T = (const float*)d_in[1];   // target
    float* Gpart = (float*)d_ws;              // NCOPY * 1024 floats

    hipMemsetAsync(Gpart, 0, NCOPY * 1024 * sizeof(float), stream);
    gram_kernel<<<1024, 512, 0, stream>>>(X, T, Gpart);
    loss_kernel<<<1, 256, 0, stream>>>(Gpart, (float*)d_out);
}